// Round 3
// baseline (184.687 us; speedup 1.0000x reference)
//
#include <hip/hip_runtime.h>

#define N_NODES 50000
#define E_EDGES 600000
#define IN_DIM  128
#define HID     256
#define OUT_DIM 128
#define CAP     64     // bucket capacity (deg ~ Poisson(12), max ~35); 64*4B = 256B d_out slot

#define RANGE_N 6250   // N_NODES / 8 ranges (one per XCD, heuristically)
#define CHUNK_E 2048   // edges per fill block (8/thread)
#define NB_FILL 2344   // 293 chunks x 8 ranges; 293*2048 = 600064 >= E
#define NB_HCVT 3125   // N*16/256, 8 floats/thread
#define NB_WCVT 384    // (65536+32768)/256
#define NB_PREP (NB_FILL + NB_HCVT + NB_WCVT)   // 5853
#define NB_MLP  782    // (N_NODES+63)/64

typedef __bf16 bf16x8 __attribute__((ext_vector_type(8)));
typedef float  f32x16 __attribute__((ext_vector_type(16)));
typedef unsigned short ushort8 __attribute__((ext_vector_type(8)));

__device__ __forceinline__ unsigned short f2bf(float f) {
    union { float f; unsigned int i; } v; v.f = f;
    unsigned int b = v.i;
    b += 0x7fffu + ((b >> 16) & 1u);   // RNE
    return (unsigned short)(b >> 16);
}
// accumulate 2 packed bf16 (one uint) into two f32 accumulators: 4 VALU insts
__device__ __forceinline__ void acc2(unsigned u, float& a0, float& a1) {
    union { unsigned i; float f; } lo, hi;
    lo.i = u << 16; hi.i = u & 0xffff0000u;
    a0 += lo.f; a1 += hi.f;
}

// ---------------------------------------------------------------------------
// Prep: [XCD-local bucket fill] + [h fp32->bf16] + [W -> swizzled bf16].
// Fill: block b -> range r = b&7 (nodes [r*6250,(r+1)*6250)), chunk = b>>3 of
// 2048 edges. Only edges whose dst falls in the block's range are handled, so
// (under round-robin block->XCD dispatch) each bucket line and its count are
// touched by ONE XCD's L2: no cross-XCD line ping-pong, L2-local atomics.
// Correctness never depends on the mapping — any XCD placement fills all
// edges exactly once. dst is scanned 8x (2.4 MB, L3-absorbed).
// Bucket lives in d_out, interleaved: node n slots at bytes [n*512+256, n*512+512).
//   w1sw flat = (((c*4 + ks)*2 + g)*256 + n)*8 + j,  k = c*64 + ks*16 + g*8 + j
//   w2sw flat = (((c*8 + ks)*2 + g)*128 + n)*8 + j,  k = c*128 + ks*16 + g*8 + j
// ---------------------------------------------------------------------------
__global__ void __launch_bounds__(256)
sage_prep(const int* __restrict__ src, const int* __restrict__ dst,
          int* __restrict__ counts, char* __restrict__ outb,
          const float* __restrict__ h, unsigned short* __restrict__ ht,
          const float* __restrict__ W1, const float* __restrict__ W2,
          unsigned short* __restrict__ w1sw, unsigned short* __restrict__ w2sw) {
    int b = blockIdx.x;
    if (b < NB_FILL) {
        int r = b & 7;
        int chunk = b >> 3;
        int e0 = chunk * CHUNK_E + threadIdx.x * 8;
        if (e0 < E_EDGES) {            // E % 8 == 0 -> whole 8-group in/out together
            int lo = r * RANGE_N, hi = lo + RANGE_N;
            const int4 d0 = *(const int4*)(dst + e0);
            const int4 d1 = *(const int4*)(dst + e0 + 4);
            int dd[8] = {d0.x, d0.y, d0.z, d0.w, d1.x, d1.y, d1.z, d1.w};
            #pragma unroll
            for (int k = 0; k < 8; ++k) {
                int d = dd[k];
                if (d >= lo && d < hi) {
                    int s = src[e0 + k];
                    int sl = atomicAdd(counts + d, 1);
                    if (sl < CAP) *((int*)(outb + (size_t)d * 512 + 256) + sl) = s;
                }
            }
        }
    } else if (b < NB_FILL + NB_HCVT) {
        int idx = (b - NB_FILL) * 256 + threadIdx.x;   // < 800000 exactly
        int n = idx >> 4, g = idx & 15;                 // 16 threads/node, 8 f/thread
        const float4 v0 = *(const float4*)(h + (size_t)n * IN_DIM + g * 8);
        const float4 v1 = *(const float4*)(h + (size_t)n * IN_DIM + g * 8 + 4);
        ushort8 o;
        o[0] = f2bf(v0.x); o[1] = f2bf(v0.y); o[2] = f2bf(v0.z); o[3] = f2bf(v0.w);
        o[4] = f2bf(v1.x); o[5] = f2bf(v1.y); o[6] = f2bf(v1.z); o[7] = f2bf(v1.w);
        *(ushort8*)(ht + (size_t)n * 128 + g * 8) = o;
    } else {
        int i1 = (b - NB_FILL - NB_HCVT) * 256 + threadIdx.x;
        if (i1 < 65536) {
            int j = i1 & 7, n = (i1 >> 3) & 255, g = (i1 >> 11) & 1, ks = (i1 >> 12) & 3, c = i1 >> 14;
            int k = c * 64 + ks * 16 + g * 8 + j;
            w1sw[i1] = f2bf(W1[(size_t)k * HID + n]);
        } else {
            int i2 = i1 - 65536;
            int j = i2 & 7, n = (i2 >> 3) & 127, g = (i2 >> 10) & 1, ks = (i2 >> 11) & 7, c = (i2 >> 14) & 1;
            int k = c * 128 + ks * 16 + g * 8 + j;
            w2sw[i2] = f2bf(W2[(size_t)k * OUT_DIM + n]);
        }
    }
}

// ---------------------------------------------------------------------------
// Fused gather + 2-layer MLP. Block = 256 threads = 4 waves = 64 rows.
// Phase G (REWRITTEN): one WAVE per node, 16 nodes/wave sequentially. The
//   64 lanes each own 2 features (one uint of packed bf16), so every neighbor
//   row is ONE fully-coalesced 256B load instruction (2 cache lines, ~2 L2
//   requests) instead of 16 scattered 16B requests, and per-row VALU is 4
//   insts/lane instead of 16. Index reads are wave-uniform (scalarizable).
//   Means -> hid_s[m][0:128], never touch HBM.
// Layer 1: chunks 0-1 A from ht (global), chunks 2-3 A from hid_s means;
//   B direct from L2-hot pre-swizzled weights (no LDS staging).
// Layouts: A[m=lane&31][k=(lane>>5)*8+j], B[k][n=lane&31],
//   C/D col=lane&31, row=(reg&3)+8*(reg>>2)+4*(lane>>5).
// Bucket rows (d_out, node n at n*512+256) are read before the same block's
// fp32 out write clobbers bytes [n*512, n*512+512): reads all precede the
// first __syncthreads, stores are after 3 more barriers; no cross-block hazard.
// ---------------------------------------------------------------------------
__global__ void __launch_bounds__(256, 4)
sage_fused(const int* __restrict__ counts,
           const unsigned short* __restrict__ ht,     // ws: bf16 [N][128]
           const unsigned short* __restrict__ w1sw,
           const unsigned short* __restrict__ w2sw,
           const float* __restrict__ b1,
           const float* __restrict__ b2,
           float* out) {                              // d_out (also holds bucket)
    __shared__ unsigned short hid_s[64][264];   // 33.8 KB (means, then hidden)

    const int t = threadIdx.x;
    const int nw = t >> 6;
    const int lane = t & 63;
    const int lr = lane & 31;
    const int lg = lane >> 5;
    const int base = blockIdx.x * 64;
    const int row0 = min(base + lr,      N_NODES - 1);
    const int row1 = min(base + 32 + lr, N_NODES - 1);

    // ---- Phase G: wave-per-node coalesced gather ---------------------------
    {
        #pragma unroll 1
        for (int i = 0; i < 16; ++i) {
            int m = nw * 16 + i;
            int node = min(base + m, N_NODES - 1);   // tail rows: dup gather, never stored
            int dg = counts[node];
            int entries = min(dg, CAP);
            const int* bk = (const int*)((const char*)out + (size_t)node * 512 + 256);
            float a0 = 0.f, a1 = 0.f;
            int e = 0;
            for (; e + 8 <= entries; e += 8) {
                const int4 q0 = *(const int4*)(bk + e);
                const int4 q1 = *(const int4*)(bk + e + 4);
                unsigned u0 = *(const unsigned*)(ht + (size_t)q0.x * 128 + lane * 2);
                unsigned u1 = *(const unsigned*)(ht + (size_t)q0.y * 128 + lane * 2);
                unsigned u2 = *(const unsigned*)(ht + (size_t)q0.z * 128 + lane * 2);
                unsigned u3 = *(const unsigned*)(ht + (size_t)q0.w * 128 + lane * 2);
                unsigned u4 = *(const unsigned*)(ht + (size_t)q1.x * 128 + lane * 2);
                unsigned u5 = *(const unsigned*)(ht + (size_t)q1.y * 128 + lane * 2);
                unsigned u6 = *(const unsigned*)(ht + (size_t)q1.z * 128 + lane * 2);
                unsigned u7 = *(const unsigned*)(ht + (size_t)q1.w * 128 + lane * 2);
                acc2(u0, a0, a1); acc2(u1, a0, a1); acc2(u2, a0, a1); acc2(u3, a0, a1);
                acc2(u4, a0, a1); acc2(u5, a0, a1); acc2(u6, a0, a1); acc2(u7, a0, a1);
            }
            if (e + 4 <= entries) {
                const int4 q = *(const int4*)(bk + e);
                unsigned u0 = *(const unsigned*)(ht + (size_t)q.x * 128 + lane * 2);
                unsigned u1 = *(const unsigned*)(ht + (size_t)q.y * 128 + lane * 2);
                unsigned u2 = *(const unsigned*)(ht + (size_t)q.z * 128 + lane * 2);
                unsigned u3 = *(const unsigned*)(ht + (size_t)q.w * 128 + lane * 2);
                acc2(u0, a0, a1); acc2(u1, a0, a1); acc2(u2, a0, a1); acc2(u3, a0, a1);
                e += 4;
            }
            for (; e < entries; ++e) {
                unsigned u = *(const unsigned*)(ht + (size_t)bk[e] * 128 + lane * 2);
                acc2(u, a0, a1);
            }
            float inv = 1.0f / (float)max(dg, 1);
            unsigned o = (unsigned)f2bf(a0 * inv) | ((unsigned)f2bf(a1 * inv) << 16);
            *(unsigned*)(&hid_s[m][lane * 2]) = o;
        }
    }

    // ---- Layer 1: hid = A (64x256) @ W1 (256x256), B direct from global ----
    f32x16 c1[2][2];   // [strip][nt]
    #pragma unroll
    for (int e2 = 0; e2 < 16; ++e2) {
        c1[0][0][e2] = 0.f; c1[0][1][e2] = 0.f; c1[1][0][e2] = 0.f; c1[1][1][e2] = 0.f;
    }

    // chunks 0,1: self features (k 0..127) from ht global — no LDS dependency
    #pragma unroll
    for (int c = 0; c < 2; ++c) {
        bf16x8 a0[4], a1[4];
        #pragma unroll
        for (int ks = 0; ks < 4; ++ks) {
            int koff = (c * 4 + ks) * 16 + lg * 8;
            a0[ks] = *(const bf16x8*)(ht + (size_t)row0 * 128 + koff);
            a1[ks] = *(const bf16x8*)(ht + (size_t)row1 * 128 + koff);
        }
        #pragma unroll
        for (int ks = 0; ks < 4; ++ks) {
            #pragma unroll
            for (int nt = 0; nt < 2; ++nt) {
                int n = nw * 64 + nt * 32 + lr;
                bf16x8 b = *(const bf16x8*)(w1sw + c * 16384 + (((ks * 2 + lg) * 256) + n) * 8);
                c1[0][nt] = __builtin_amdgcn_mfma_f32_32x32x16_bf16(a0[ks], b, c1[0][nt], 0, 0, 0);
                c1[1][nt] = __builtin_amdgcn_mfma_f32_32x32x16_bf16(a1[ks], b, c1[1][nt], 0, 0, 0);
            }
        }
    }

    __syncthreads();    // all gather writes to hid_s visible

    // chunks 2,3: neighbor means (k 128..255) from LDS
    #pragma unroll
    for (int c = 2; c < 4; ++c) {
        bf16x8 a0[4], a1[4];
        #pragma unroll
        for (int ks = 0; ks < 4; ++ks) {
            int koff = (c - 2) * 64 + ks * 16 + lg * 8;
            a0[ks] = *(const bf16x8*)(&hid_s[lr][koff]);
            a1[ks] = *(const bf16x8*)(&hid_s[32 + lr][koff]);
        }
        #pragma unroll
        for (int ks = 0; ks < 4; ++ks) {
            #pragma unroll
            for (int nt = 0; nt < 2; ++nt) {
                int n = nw * 64 + nt * 32 + lr;
                bf16x8 b = *(const bf16x8*)(w1sw + c * 16384 + (((ks * 2 + lg) * 256) + n) * 8);
                c1[0][nt] = __builtin_amdgcn_mfma_f32_32x32x16_bf16(a0[ks], b, c1[0][nt], 0, 0, 0);
                c1[1][nt] = __builtin_amdgcn_mfma_f32_32x32x16_bf16(a1[ks], b, c1[1][nt], 0, 0, 0);
            }
        }
    }

    __syncthreads();    // all mean reads done before epilogue-1 overwrites

    // ---- epilogue 1: + b1 -> bf16 -> hid_s (row-major [m][k]) --------------
    #pragma unroll
    for (int nt = 0; nt < 2; ++nt) {
        int col = nw * 64 + nt * 32 + lr;
        float bias = b1[col];
        #pragma unroll
        for (int s = 0; s < 2; ++s) {
            #pragma unroll
            for (int reg = 0; reg < 16; ++reg) {
                int m = s * 32 + (reg & 3) + 8 * (reg >> 2) + 4 * lg;
                hid_s[m][col] = f2bf(c1[s][nt][reg] + bias);
            }
        }
    }
    __syncthreads();    // hidden tile visible

    // ---- Layer 2: out = hid (64x256) @ W2 (256x128), B direct from global --
    f32x16 c2[2];
    #pragma unroll
    for (int e2 = 0; e2 < 16; ++e2) { c2[0][e2] = 0.f; c2[1][e2] = 0.f; }

    #pragma unroll
    for (int c = 0; c < 2; ++c) {
        #pragma unroll
        for (int ks = 0; ks < 8; ++ks) {
            bf16x8 b = *(const bf16x8*)(w2sw + c * 16384 + ((ks * 2 + lg) * 128 + nw * 32 + lr) * 8);
            int koff = c * 128 + ks * 16 + lg * 8;
            bf16x8 ah0 = *(const bf16x8*)(&hid_s[lr][koff]);
            bf16x8 ah1 = *(const bf16x8*)(&hid_s[32 + lr][koff]);
            c2[0] = __builtin_amdgcn_mfma_f32_32x32x16_bf16(ah0, b, c2[0], 0, 0, 0);
            c2[1] = __builtin_amdgcn_mfma_f32_32x32x16_bf16(ah1, b, c2[1], 0, 0, 0);
        }
    }

    // ---- epilogue 2: + b2, relu, store fp32 (clobbers own bucket rows only)
    {
        int col = nw * 32 + lr;
        float bias = b2[col];
        #pragma unroll
        for (int s = 0; s < 2; ++s) {
            #pragma unroll
            for (int reg = 0; reg < 16; ++reg) {
                int m = s * 32 + (reg & 3) + 8 * (reg >> 2) + 4 * lg;
                int n = base + m;
                if (n < N_NODES)
                    out[(size_t)n * OUT_DIM + col] = fmaxf(c2[s][reg] + bias, 0.0f);
            }
        }
    }
}

extern "C" void kernel_launch(void* const* d_in, const int* in_sizes, int n_in,
                              void* d_out, int out_size, void* d_ws, size_t ws_size,
                              hipStream_t stream) {
    const float* h   = (const float*)d_in[0];
    const int*   src = (const int*)d_in[1];
    const int*   dst = (const int*)d_in[2];
    const float* W1  = (const float*)d_in[3];
    const float* b1  = (const float*)d_in[4];
    const float* W2  = (const float*)d_in[5];
    const float* b2  = (const float*)d_in[6];
    float* out = (float*)d_out;

    // ws: counts [50000 int] | w1sw [65536 bf16] | w2sw [32768 bf16] | ht_h [50000*128 bf16]
    // total ~13.2 MB (bucket lives in d_out).
    int* counts = (int*)d_ws;
    unsigned short* w1sw = (unsigned short*)(counts + N_NODES);
    unsigned short* w2sw = w1sw + 65536;
    unsigned short* ht   = w2sw + 32768;   // 16B aligned

    hipMemsetAsync(counts, 0, N_NODES * sizeof(int), stream);

    sage_prep<<<NB_PREP, 256, 0, stream>>>(
        src, dst, counts, (char*)d_out, h, ht, W1, W2, w1sw, w2sw);

    sage_fused<<<NB_MLP, 256, 0, stream>>>(counts, ht, w1sw, w2sw, b1, b2, out);
}

// Round 4
// 177.669 us; speedup vs baseline: 1.0395x; 1.0395x over previous
//
#include <hip/hip_runtime.h>

#define N_NODES 50000
#define E_EDGES 600000
#define IN_DIM  128
#define HID     256
#define OUT_DIM 128
#define CAP     64     // bucket capacity (deg ~ Poisson(12), max ~35); 64*4B = 256B d_out slot

#define RANGE_N 6250   // N_NODES / 8 ranges (one per XCD, heuristically)
#define CHUNK_E 2048   // edges per fill block (8/thread)
#define NB_FILL 2344   // 293 chunks x 8 ranges; 293*2048 = 600064 >= E
#define NB_HCVT 3125   // N*16/256, 8 floats/thread
#define NB_WCVT 384    // (65536+32768)/256
#define NB_CVT  (NB_HCVT + NB_WCVT)   // 3509
#define NB_MLP  782    // (N_NODES+63)/64

typedef __bf16 bf16x8 __attribute__((ext_vector_type(8)));
typedef float  f32x16 __attribute__((ext_vector_type(16)));
typedef unsigned short ushort8 __attribute__((ext_vector_type(8)));

__device__ __forceinline__ unsigned short f2bf(float f) {
    union { float f; unsigned int i; } v; v.f = f;
    unsigned int b = v.i;
    b += 0x7fffu + ((b >> 16) & 1u);   // RNE
    return (unsigned short)(b >> 16);
}
// accumulate 2 packed bf16 (one uint) into two f32 accumulators: 4 VALU insts
__device__ __forceinline__ void acc2(unsigned u, float& a0, float& a1) {
    union { unsigned i; float f; } lo, hi;
    lo.i = u << 16; hi.i = u & 0xffff0000u;
    a0 += lo.f; a1 += hi.f;
}

// ---------------------------------------------------------------------------
// Fill kernel (split out for rocprof attribution). XCD-local: block b ->
// range r = b&7 (nodes [r*6250,(r+1)*6250)), chunk = b>>3 of 2048 edges.
// Under round-robin block->XCD dispatch each bucket line + count is owned by
// one XCD's L2 (no cross-XCD line ping-pong). Correct under ANY placement.
// Bucket lives in d_out: node n slots at bytes [n*512+256, n*512+512).
// ---------------------------------------------------------------------------
__global__ void __launch_bounds__(256)
sage_fill(const int* __restrict__ src, const int* __restrict__ dst,
          int* __restrict__ counts, char* __restrict__ outb) {
    int b = blockIdx.x;
    int r = b & 7;
    int chunk = b >> 3;
    int e0 = chunk * CHUNK_E + threadIdx.x * 8;
    if (e0 < E_EDGES) {            // E % 8 == 0 -> whole 8-group in/out together
        int lo = r * RANGE_N, hi = lo + RANGE_N;
        const int4 d0 = *(const int4*)(dst + e0);
        const int4 d1 = *(const int4*)(dst + e0 + 4);
        int dd[8] = {d0.x, d0.y, d0.z, d0.w, d1.x, d1.y, d1.z, d1.w};
        #pragma unroll
        for (int k = 0; k < 8; ++k) {
            int d = dd[k];
            if (d >= lo && d < hi) {
                int s = src[e0 + k];
                int sl = atomicAdd(counts + d, 1);
                if (sl < CAP) *((int*)(outb + (size_t)d * 512 + 256) + sl) = s;
            }
        }
    }
}

// ---------------------------------------------------------------------------
// Convert kernel: [h fp32->bf16, 8/thread] + [W1/W2 -> swizzled bf16].
//   w1sw flat = (((c*4 + ks)*2 + g)*256 + n)*8 + j,  k = c*64 + ks*16 + g*8 + j
//   w2sw flat = (((c*8 + ks)*2 + g)*128 + n)*8 + j,  k = c*128 + ks*16 + g*8 + j
// ---------------------------------------------------------------------------
__global__ void __launch_bounds__(256)
sage_cvt(const float* __restrict__ h, unsigned short* __restrict__ ht,
         const float* __restrict__ W1, const float* __restrict__ W2,
         unsigned short* __restrict__ w1sw, unsigned short* __restrict__ w2sw) {
    int b = blockIdx.x;
    if (b < NB_HCVT) {
        int idx = b * 256 + threadIdx.x;   // < 800000 exactly
        int n = idx >> 4, g = idx & 15;     // 16 threads/node, 8 f/thread
        const float4 v0 = *(const float4*)(h + (size_t)n * IN_DIM + g * 8);
        const float4 v1 = *(const float4*)(h + (size_t)n * IN_DIM + g * 8 + 4);
        ushort8 o;
        o[0] = f2bf(v0.x); o[1] = f2bf(v0.y); o[2] = f2bf(v0.z); o[3] = f2bf(v0.w);
        o[4] = f2bf(v1.x); o[5] = f2bf(v1.y); o[6] = f2bf(v1.z); o[7] = f2bf(v1.w);
        *(ushort8*)(ht + (size_t)n * 128 + g * 8) = o;
    } else {
        int i1 = (b - NB_HCVT) * 256 + threadIdx.x;
        if (i1 < 65536) {
            int j = i1 & 7, n = (i1 >> 3) & 255, g = (i1 >> 11) & 1, ks = (i1 >> 12) & 3, c = i1 >> 14;
            int k = c * 64 + ks * 16 + g * 8 + j;
            w1sw[i1] = f2bf(W1[(size_t)k * HID + n]);
        } else {
            int i2 = i1 - 65536;
            int j = i2 & 7, n = (i2 >> 3) & 127, g = (i2 >> 10) & 1, ks = (i2 >> 11) & 7, c = (i2 >> 14) & 1;
            int k = c * 128 + ks * 16 + g * 8 + j;
            w2sw[i2] = f2bf(W2[(size_t)k * OUT_DIM + n]);
        }
    }
}

// ---------------------------------------------------------------------------
// Fused gather + 2-layer MLP. Block = 256 threads = 4 waves = 64 rows.
// Phase G: wave-per-node COALESCED rows (64 lanes x 4B = one 256B load/row)
//   with 4 NODES INTERLEAVED per wave (4 independent accumulator chains) and
//   a two-pass body (issue all <=16 row loads into regs, then accumulate) so
//   ~16 coalesced loads stay in flight per wave — coalescing of r3 + MLP of
//   r2. Degree guards are wave-uniform scalar branches; neighbor indices are
//   readfirstlane'd so row bases are SGPR-computed. Means -> hid_s[m][0:128].
// Layer 1: chunks 0-1 A from ht (global), chunks 2-3 A from hid_s means;
//   B direct from L2-hot pre-swizzled weights (no LDS staging).
// Layouts: A[m=lane&31][k=(lane>>5)*8+j], B[k][n=lane&31],
//   C/D col=lane&31, row=(reg&3)+8*(reg>>2)+4*(lane>>5).
// Bucket rows (d_out, node n at n*512+256) are read before the same block's
// fp32 out write clobbers bytes [n*512, n*512+512): all bucket reads precede
// the first __syncthreads, stores are after 3 more barriers; no cross-block
// hazard (only the owning block touches row n's bytes).
// ---------------------------------------------------------------------------
__global__ void __launch_bounds__(256, 4)
sage_fused(const int* __restrict__ counts,
           const unsigned short* __restrict__ ht,     // ws: bf16 [N][128]
           const unsigned short* __restrict__ w1sw,
           const unsigned short* __restrict__ w2sw,
           const float* __restrict__ b1,
           const float* __restrict__ b2,
           float* out) {                              // d_out (also holds bucket)
    __shared__ unsigned short hid_s[64][264];   // 33.8 KB (means, then hidden)

    const int t = threadIdx.x;
    const int nw = t >> 6;
    const int lane = t & 63;
    const int lr = lane & 31;
    const int lg = lane >> 5;
    const int base = blockIdx.x * 64;
    const int row0 = min(base + lr,      N_NODES - 1);
    const int row1 = min(base + 32 + lr, N_NODES - 1);

    // ---- Phase G: coalesced gather, 4 nodes interleaved per wave -----------
    {
        #pragma unroll 1
        for (int g = 0; g < 4; ++g) {
            const int m0 = nw * 16 + g * 4;
            float a0[4], a1[4];
            int deg[4], ent[4];
            const int* bk[4];
            int4 q[4];
            int em = 0;
            #pragma unroll
            for (int j = 0; j < 4; ++j) {
                a0[j] = 0.f; a1[j] = 0.f;
                int node = min(base + m0 + j, N_NODES - 1);  // tail rows: dup gather, never stored
                deg[j] = __builtin_amdgcn_readfirstlane(counts[node]);
                ent[j] = min(deg[j], CAP);
                em = max(em, ent[j]);
                bk[j] = (const int*)((const char*)out + (size_t)node * 512 + 256);
                q[j] = *(const int4*)(bk[j]);       // slot 0..3 (allocated; guarded use)
            }
            #pragma unroll 1
            for (int p = 0; p < em; p += 4) {
                int4 nx[4];
                #pragma unroll
                for (int j = 0; j < 4; ++j)
                    nx[j] = *(const int4*)(bk[j] + min(p + 4, CAP - 4));  // prefetch (guarded use)
                unsigned uu[16];
                // pass 1: issue all live row loads (fully unrolled -> static idx)
                #pragma unroll
                for (int k = 0; k < 4; ++k) {
                    #pragma unroll
                    for (int j = 0; j < 4; ++j) {
                        if (p + k < ent[j]) {   // wave-uniform scalar branch
                            int idx = (k == 0) ? q[j].x : (k == 1) ? q[j].y
                                    : (k == 2) ? q[j].z : q[j].w;
                            idx = __builtin_amdgcn_readfirstlane(idx);
                            uu[k * 4 + j] = *(const unsigned*)(ht + (size_t)idx * 128 + lane * 2);
                        }
                    }
                }
                // pass 2: accumulate
                #pragma unroll
                for (int k = 0; k < 4; ++k) {
                    #pragma unroll
                    for (int j = 0; j < 4; ++j) {
                        if (p + k < ent[j])
                            acc2(uu[k * 4 + j], a0[j], a1[j]);
                    }
                }
                #pragma unroll
                for (int j = 0; j < 4; ++j) q[j] = nx[j];
            }
            #pragma unroll
            for (int j = 0; j < 4; ++j) {
                float inv = 1.0f / (float)max(deg[j], 1);
                unsigned o = (unsigned)f2bf(a0[j] * inv) | ((unsigned)f2bf(a1[j] * inv) << 16);
                *(unsigned*)(&hid_s[m0 + j][lane * 2]) = o;
            }
        }
    }

    // ---- Layer 1: hid = A (64x256) @ W1 (256x256), B direct from global ----
    f32x16 c1[2][2];   // [strip][nt]
    #pragma unroll
    for (int e2 = 0; e2 < 16; ++e2) {
        c1[0][0][e2] = 0.f; c1[0][1][e2] = 0.f; c1[1][0][e2] = 0.f; c1[1][1][e2] = 0.f;
    }

    // chunks 0,1: self features (k 0..127) from ht global — no LDS dependency
    #pragma unroll
    for (int c = 0; c < 2; ++c) {
        bf16x8 a0[4], a1[4];
        #pragma unroll
        for (int ks = 0; ks < 4; ++ks) {
            int koff = (c * 4 + ks) * 16 + lg * 8;
            a0[ks] = *(const bf16x8*)(ht + (size_t)row0 * 128 + koff);
            a1[ks] = *(const bf16x8*)(ht + (size_t)row1 * 128 + koff);
        }
        #pragma unroll
        for (int ks = 0; ks < 4; ++ks) {
            #pragma unroll
            for (int nt = 0; nt < 2; ++nt) {
                int n = nw * 64 + nt * 32 + lr;
                bf16x8 b = *(const bf16x8*)(w1sw + c * 16384 + (((ks * 2 + lg) * 256) + n) * 8);
                c1[0][nt] = __builtin_amdgcn_mfma_f32_32x32x16_bf16(a0[ks], b, c1[0][nt], 0, 0, 0);
                c1[1][nt] = __builtin_amdgcn_mfma_f32_32x32x16_bf16(a1[ks], b, c1[1][nt], 0, 0, 0);
            }
        }
    }

    __syncthreads();    // all gather writes to hid_s visible

    // chunks 2,3: neighbor means (k 128..255) from LDS
    #pragma unroll
    for (int c = 2; c < 4; ++c) {
        bf16x8 a0[4], a1[4];
        #pragma unroll
        for (int ks = 0; ks < 4; ++ks) {
            int koff = (c - 2) * 64 + ks * 16 + lg * 8;
            a0[ks] = *(const bf16x8*)(&hid_s[lr][koff]);
            a1[ks] = *(const bf16x8*)(&hid_s[32 + lr][koff]);
        }
        #pragma unroll
        for (int ks = 0; ks < 4; ++ks) {
            #pragma unroll
            for (int nt = 0; nt < 2; ++nt) {
                int n = nw * 64 + nt * 32 + lr;
                bf16x8 b = *(const bf16x8*)(w1sw + c * 16384 + (((ks * 2 + lg) * 256) + n) * 8);
                c1[0][nt] = __builtin_amdgcn_mfma_f32_32x32x16_bf16(a0[ks], b, c1[0][nt], 0, 0, 0);
                c1[1][nt] = __builtin_amdgcn_mfma_f32_32x32x16_bf16(a1[ks], b, c1[1][nt], 0, 0, 0);
            }
        }
    }

    __syncthreads();    // all mean reads done before epilogue-1 overwrites

    // ---- epilogue 1: + b1 -> bf16 -> hid_s (row-major [m][k]) --------------
    #pragma unroll
    for (int nt = 0; nt < 2; ++nt) {
        int col = nw * 64 + nt * 32 + lr;
        float bias = b1[col];
        #pragma unroll
        for (int s = 0; s < 2; ++s) {
            #pragma unroll
            for (int reg = 0; reg < 16; ++reg) {
                int m = s * 32 + (reg & 3) + 8 * (reg >> 2) + 4 * lg;
                hid_s[m][col] = f2bf(c1[s][nt][reg] + bias);
            }
        }
    }
    __syncthreads();    // hidden tile visible

    // ---- Layer 2: out = hid (64x256) @ W2 (256x128), B direct from global --
    f32x16 c2[2];
    #pragma unroll
    for (int e2 = 0; e2 < 16; ++e2) { c2[0][e2] = 0.f; c2[1][e2] = 0.f; }

    #pragma unroll
    for (int c = 0; c < 2; ++c) {
        #pragma unroll
        for (int ks = 0; ks < 8; ++ks) {
            bf16x8 b = *(const bf16x8*)(w2sw + c * 16384 + ((ks * 2 + lg) * 128 + nw * 32 + lr) * 8);
            int koff = c * 128 + ks * 16 + lg * 8;
            bf16x8 ah0 = *(const bf16x8*)(&hid_s[lr][koff]);
            bf16x8 ah1 = *(const bf16x8*)(&hid_s[32 + lr][koff]);
            c2[0] = __builtin_amdgcn_mfma_f32_32x32x16_bf16(ah0, b, c2[0], 0, 0, 0);
            c2[1] = __builtin_amdgcn_mfma_f32_32x32x16_bf16(ah1, b, c2[1], 0, 0, 0);
        }
    }

    // ---- epilogue 2: + b2, relu, store fp32 (clobbers own bucket rows only)
    {
        int col = nw * 32 + lr;
        float bias = b2[col];
        #pragma unroll
        for (int s = 0; s < 2; ++s) {
            #pragma unroll
            for (int reg = 0; reg < 16; ++reg) {
                int m = s * 32 + (reg & 3) + 8 * (reg >> 2) + 4 * lg;
                int n = base + m;
                if (n < N_NODES)
                    out[(size_t)n * OUT_DIM + col] = fmaxf(c2[s][reg] + bias, 0.0f);
            }
        }
    }
}

extern "C" void kernel_launch(void* const* d_in, const int* in_sizes, int n_in,
                              void* d_out, int out_size, void* d_ws, size_t ws_size,
                              hipStream_t stream) {
    const float* h   = (const float*)d_in[0];
    const int*   src = (const int*)d_in[1];
    const int*   dst = (const int*)d_in[2];
    const float* W1  = (const float*)d_in[3];
    const float* b1  = (const float*)d_in[4];
    const float* W2  = (const float*)d_in[5];
    const float* b2  = (const float*)d_in[6];
    float* out = (float*)d_out;

    // ws: counts [50000 int] | w1sw [65536 bf16] | w2sw [32768 bf16] | ht_h [50000*128 bf16]
    // total ~13.2 MB (bucket lives in d_out).
    int* counts = (int*)d_ws;
    unsigned short* w1sw = (unsigned short*)(counts + N_NODES);
    unsigned short* w2sw = w1sw + 65536;
    unsigned short* ht   = w2sw + 32768;   // 16B aligned

    hipMemsetAsync(counts, 0, N_NODES * sizeof(int), stream);

    sage_fill<<<NB_FILL, 256, 0, stream>>>(src, dst, counts, (char*)d_out);

    sage_cvt<<<NB_CVT, 256, 0, stream>>>(h, ht, W1, W2, w1sw, w2sw);

    sage_fused<<<NB_MLP, 256, 0, stream>>>(counts, ht, w1sw, w2sw, b1, b2, out);
}

// Round 5
// 169.566 us; speedup vs baseline: 1.0892x; 1.0478x over previous
//
#include <hip/hip_runtime.h>

#define N_NODES 50000
#define E_EDGES 600000
#define IN_DIM  128
#define HID     256
#define OUT_DIM 128
#define CAP     64     // bucket capacity (deg ~ Poisson(12), max ~35); 64*4B = 256B d_out slot
#define ZROW    N_NODES   // sentinel ht row of zeros (row 50000)

#define RANGE_N 6250   // N_NODES / 8 ranges (one per XCD, heuristically)
#define CHUNK_E 2048   // edges per fill block (8/thread)
#define NB_FILL 2344   // 293 chunks x 8 ranges; 293*2048 = 600064 >= E
#define NB_HCVT 3125   // N*16/256, 8 floats/thread
#define NB_WCVT 384    // (65536+32768)/256
#define NB_PREP (NB_FILL + NB_HCVT + NB_WCVT + 1)   // 5854 (last block zeroes ZROW)
#define NB_MLP  782    // (N_NODES+63)/64

typedef __bf16 bf16x8 __attribute__((ext_vector_type(8)));
typedef float  f32x16 __attribute__((ext_vector_type(16)));
typedef unsigned short ushort8 __attribute__((ext_vector_type(8)));

__device__ __forceinline__ unsigned short f2bf(float f) {
    union { float f; unsigned int i; } v; v.f = f;
    unsigned int b = v.i;
    b += 0x7fffu + ((b >> 16) & 1u);   // RNE
    return (unsigned short)(b >> 16);
}
// accumulate 2 packed bf16 (one uint) into two f32 accumulators: 4 VALU insts
__device__ __forceinline__ void acc2(unsigned u, float& a0, float& a1) {
    union { unsigned i; float f; } lo, hi;
    lo.i = u << 16; hi.i = u & 0xffff0000u;
    a0 += lo.f; a1 += hi.f;
}

// ---------------------------------------------------------------------------
// Prep (merged): [XCD-local bucket fill] + [h fp32->bf16] + [W -> swz bf16]
// + [zero sentinel row]. Fill blocks dispatch first; cvt blocks co-resident
// overlap the fill's atomic-latency phase.
// Fill: block b -> range r = b&7 (nodes [r*6250,(r+1)*6250)), chunk b>>3 of
// 2048 edges; only edges with dst in-range are handled -> under round-robin
// block->XCD dispatch each bucket line + count is owned by one XCD's L2.
// Correct under ANY placement. dst scanned 8x (2.4 MB, L3-absorbed).
// Bucket lives in d_out: node n slots at bytes [n*512+256, n*512+512).
//   w1sw flat = (((c*4 + ks)*2 + g)*256 + n)*8 + j,  k = c*64 + ks*16 + g*8 + j
//   w2sw flat = (((c*8 + ks)*2 + g)*128 + n)*8 + j,  k = c*128 + ks*16 + g*8 + j
// ---------------------------------------------------------------------------
__global__ void __launch_bounds__(256)
sage_prep(const int* __restrict__ src, const int* __restrict__ dst,
          int* __restrict__ counts, char* __restrict__ outb,
          const float* __restrict__ h, unsigned short* __restrict__ ht,
          const float* __restrict__ W1, const float* __restrict__ W2,
          unsigned short* __restrict__ w1sw, unsigned short* __restrict__ w2sw) {
    int b = blockIdx.x;
    if (b < NB_FILL) {
        int r = b & 7;
        int chunk = b >> 3;
        int e0 = chunk * CHUNK_E + threadIdx.x * 8;
        if (e0 < E_EDGES) {            // E % 8 == 0 -> whole 8-group in/out together
            int lo = r * RANGE_N, hi = lo + RANGE_N;
            const int4 d0 = *(const int4*)(dst + e0);
            const int4 d1 = *(const int4*)(dst + e0 + 4);
            int dd[8] = {d0.x, d0.y, d0.z, d0.w, d1.x, d1.y, d1.z, d1.w};
            #pragma unroll
            for (int k = 0; k < 8; ++k) {
                int d = dd[k];
                if (d >= lo && d < hi) {
                    int s = src[e0 + k];
                    int sl = atomicAdd(counts + d, 1);
                    if (sl < CAP) *((int*)(outb + (size_t)d * 512 + 256) + sl) = s;
                }
            }
        }
    } else if (b < NB_FILL + NB_HCVT) {
        int idx = (b - NB_FILL) * 256 + threadIdx.x;   // < 800000 exactly
        int n = idx >> 4, g = idx & 15;                 // 16 threads/node, 8 f/thread
        const float4 v0 = *(const float4*)(h + (size_t)n * IN_DIM + g * 8);
        const float4 v1 = *(const float4*)(h + (size_t)n * IN_DIM + g * 8 + 4);
        ushort8 o;
        o[0] = f2bf(v0.x); o[1] = f2bf(v0.y); o[2] = f2bf(v0.z); o[3] = f2bf(v0.w);
        o[4] = f2bf(v1.x); o[5] = f2bf(v1.y); o[6] = f2bf(v1.z); o[7] = f2bf(v1.w);
        *(ushort8*)(ht + (size_t)n * 128 + g * 8) = o;
    } else if (b < NB_FILL + NB_HCVT + NB_WCVT) {
        int i1 = (b - NB_FILL - NB_HCVT) * 256 + threadIdx.x;
        if (i1 < 65536) {
            int j = i1 & 7, n = (i1 >> 3) & 255, g = (i1 >> 11) & 1, ks = (i1 >> 12) & 3, c = i1 >> 14;
            int k = c * 64 + ks * 16 + g * 8 + j;
            w1sw[i1] = f2bf(W1[(size_t)k * HID + n]);
        } else {
            int i2 = i1 - 65536;
            int j = i2 & 7, n = (i2 >> 3) & 127, g = (i2 >> 10) & 1, ks = (i2 >> 11) & 7, c = (i2 >> 14) & 1;
            int k = c * 128 + ks * 16 + g * 8 + j;
            w2sw[i2] = f2bf(W2[(size_t)k * OUT_DIM + n]);
        }
    } else {
        // zero the sentinel row (ht row ZROW = 50000): dead gather slots load it
        if (threadIdx.x < 64)
            *(unsigned*)(ht + (size_t)ZROW * 128 + threadIdx.x * 2) = 0u;
    }
}

// ---------------------------------------------------------------------------
// Fused gather + 2-layer MLP. Block = 256 threads = 4 waves = 64 rows.
// Phase G (BRANCH-FREE): wave-per-node coalesced rows (64 lanes x 4B = one
//   256B load/row), 4 nodes interleaved per wave. Dead slots (p+k >= ent[j])
//   select the ZERO SENTINEL row via scalar cselect instead of branching ->
//   straight-line body: 16 unconditional loads back-to-back, precise vmcnt,
//   ~16 loads always in flight per wave (r4's 32 branches collapsed the
//   pipeline to ~2 TB/s; this is the fix). Also copies each node's OWN row
//   into hid_s[m][128:256] (coalesced, latency-hidden) so layer-1 never
//   re-reads ht from global. Means -> hid_s[m][0:128].
// Layer 1: ALL A-frags from LDS (self at col 128+, means at col 0+);
//   B direct from L2-hot pre-swizzled weights (no LDS staging).
// Layouts: A[m=lane&31][k=(lane>>5)*8+j], B[k][n=lane&31],
//   C/D col=lane&31, row=(reg&3)+8*(reg>>2)+4*(lane>>5).
// Bucket rows (d_out, node n at n*512+256) are read before the same block's
// fp32 out write clobbers bytes [n*512, n*512+512): all bucket reads precede
// the first __syncthreads, stores after 3 more barriers; no cross-block
// hazard (only the owning block touches row n's bytes).
// ---------------------------------------------------------------------------
__global__ void __launch_bounds__(256, 4)
sage_fused(const int* __restrict__ counts,
           const unsigned short* __restrict__ ht,     // ws: bf16 [N+1][128]
           const unsigned short* __restrict__ w1sw,
           const unsigned short* __restrict__ w2sw,
           const float* __restrict__ b1,
           const float* __restrict__ b2,
           float* out) {                              // d_out (also holds bucket)
    __shared__ unsigned short hid_s[64][264];   // 33.8 KB: [0:128)=means, [128:256)=self

    const int t = threadIdx.x;
    const int nw = t >> 6;
    const int lane = t & 63;
    const int lr = lane & 31;
    const int lg = lane >> 5;
    const int base = blockIdx.x * 64;

    // ---- Phase G: branch-free coalesced gather, 4 nodes/wave interleaved ---
    {
        #pragma unroll 1
        for (int g = 0; g < 4; ++g) {
            const int m0 = nw * 16 + g * 4;
            float a0[4], a1[4];
            int deg[4], ent[4];
            const int* bk[4];
            int4 q[4];
            int em = 0;
            #pragma unroll
            for (int j = 0; j < 4; ++j) {
                a0[j] = 0.f; a1[j] = 0.f;
                int node = min(base + m0 + j, N_NODES - 1);  // tail rows: dup gather, never stored
                deg[j] = __builtin_amdgcn_readfirstlane(counts[node]);
                ent[j] = min(deg[j], CAP);
                em = max(em, ent[j]);
                bk[j] = (const int*)((const char*)out + (size_t)node * 512 + 256);
                q[j] = *(const int4*)(bk[j]);       // slots 0..3 (allocated; sel-guarded use)
                // own row -> hid_s[m][128:256] (coalesced; hidden among gather loads)
                unsigned self = *(const unsigned*)(ht + (size_t)node * 128 + lane * 2);
                *(unsigned*)(&hid_s[m0 + j][128 + lane * 2]) = self;
            }
            #pragma unroll 1
            for (int p = 0; p < em; p += 4) {
                int4 nx[4];
                #pragma unroll
                for (int j = 0; j < 4; ++j)
                    nx[j] = *(const int4*)(bk[j] + min(p + 4, CAP - 4));  // prefetch (sel-guarded use)
                unsigned uu[16];
                // pass 1: 16 unconditional loads; dead slots -> zero sentinel row
                #pragma unroll
                for (int k = 0; k < 4; ++k) {
                    #pragma unroll
                    for (int j = 0; j < 4; ++j) {
                        int idx = (k == 0) ? q[j].x : (k == 1) ? q[j].y
                                : (k == 2) ? q[j].z : q[j].w;
                        idx = __builtin_amdgcn_readfirstlane(idx);
                        idx = (p + k < ent[j]) ? idx : ZROW;   // scalar cselect, no branch
                        uu[k * 4 + j] = *(const unsigned*)(ht + (size_t)idx * 128 + lane * 2);
                    }
                }
                // pass 2: unconditional accumulate (sentinel adds 0.0)
                #pragma unroll
                for (int k = 0; k < 4; ++k) {
                    #pragma unroll
                    for (int j = 0; j < 4; ++j)
                        acc2(uu[k * 4 + j], a0[j], a1[j]);
                }
                #pragma unroll
                for (int j = 0; j < 4; ++j) q[j] = nx[j];
            }
            #pragma unroll
            for (int j = 0; j < 4; ++j) {
                float inv = 1.0f / (float)max(deg[j], 1);
                unsigned o = (unsigned)f2bf(a0[j] * inv) | ((unsigned)f2bf(a1[j] * inv) << 16);
                *(unsigned*)(&hid_s[m0 + j][lane * 2]) = o;
            }
        }
    }

    __syncthreads();    // gather writes (means + self rows) visible to all waves

    // ---- Layer 1: hid = A (64x256) @ W1 (256x256); A from LDS, B from L2 ---
    f32x16 c1[2][2];   // [strip][nt]
    #pragma unroll
    for (int e2 = 0; e2 < 16; ++e2) {
        c1[0][0][e2] = 0.f; c1[0][1][e2] = 0.f; c1[1][0][e2] = 0.f; c1[1][1][e2] = 0.f;
    }

    #pragma unroll
    for (int c = 0; c < 4; ++c) {
        bf16x8 a0[4], a1[4];
        #pragma unroll
        for (int ks = 0; ks < 4; ++ks) {
            // k 0..127 = self features (LDS col 128+), k 128..255 = means (LDS col 0+)
            int koff = (c < 2) ? (128 + c * 64 + ks * 16 + lg * 8)
                               : ((c - 2) * 64 + ks * 16 + lg * 8);
            a0[ks] = *(const bf16x8*)(&hid_s[lr][koff]);
            a1[ks] = *(const bf16x8*)(&hid_s[32 + lr][koff]);
        }
        #pragma unroll
        for (int ks = 0; ks < 4; ++ks) {
            #pragma unroll
            for (int nt = 0; nt < 2; ++nt) {
                int n = nw * 64 + nt * 32 + lr;
                bf16x8 b = *(const bf16x8*)(w1sw + c * 16384 + (((ks * 2 + lg) * 256) + n) * 8);
                c1[0][nt] = __builtin_amdgcn_mfma_f32_32x32x16_bf16(a0[ks], b, c1[0][nt], 0, 0, 0);
                c1[1][nt] = __builtin_amdgcn_mfma_f32_32x32x16_bf16(a1[ks], b, c1[1][nt], 0, 0, 0);
            }
        }
    }

    __syncthreads();    // all A reads done before epilogue-1 overwrites

    // ---- epilogue 1: + b1 -> bf16 -> hid_s (row-major [m][k]) --------------
    #pragma unroll
    for (int nt = 0; nt < 2; ++nt) {
        int col = nw * 64 + nt * 32 + lr;
        float bias = b1[col];
        #pragma unroll
        for (int s = 0; s < 2; ++s) {
            #pragma unroll
            for (int reg = 0; reg < 16; ++reg) {
                int m = s * 32 + (reg & 3) + 8 * (reg >> 2) + 4 * lg;
                hid_s[m][col] = f2bf(c1[s][nt][reg] + bias);
            }
        }
    }
    __syncthreads();    // hidden tile visible

    // ---- Layer 2: out = hid (64x256) @ W2 (256x128), B direct from global --
    f32x16 c2[2];
    #pragma unroll
    for (int e2 = 0; e2 < 16; ++e2) { c2[0][e2] = 0.f; c2[1][e2] = 0.f; }

    #pragma unroll
    for (int c = 0; c < 2; ++c) {
        #pragma unroll
        for (int ks = 0; ks < 8; ++ks) {
            bf16x8 b = *(const bf16x8*)(w2sw + c * 16384 + ((ks * 2 + lg) * 128 + nw * 32 + lr) * 8);
            int koff = c * 128 + ks * 16 + lg * 8;
            bf16x8 ah0 = *(const bf16x8*)(&hid_s[lr][koff]);
            bf16x8 ah1 = *(const bf16x8*)(&hid_s[32 + lr][koff]);
            c2[0] = __builtin_amdgcn_mfma_f32_32x32x16_bf16(ah0, b, c2[0], 0, 0, 0);
            c2[1] = __builtin_amdgcn_mfma_f32_32x32x16_bf16(ah1, b, c2[1], 0, 0, 0);
        }
    }

    // ---- epilogue 2: + b2, relu, store fp32 (clobbers own bucket rows only)
    {
        int col = nw * 32 + lr;
        float bias = b2[col];
        #pragma unroll
        for (int s = 0; s < 2; ++s) {
            #pragma unroll
            for (int reg = 0; reg < 16; ++reg) {
                int m = s * 32 + (reg & 3) + 8 * (reg >> 2) + 4 * lg;
                int n = base + m;
                if (n < N_NODES)
                    out[(size_t)n * OUT_DIM + col] = fmaxf(c2[s][reg] + bias, 0.0f);
            }
        }
    }
}

extern "C" void kernel_launch(void* const* d_in, const int* in_sizes, int n_in,
                              void* d_out, int out_size, void* d_ws, size_t ws_size,
                              hipStream_t stream) {
    const float* h   = (const float*)d_in[0];
    const int*   src = (const int*)d_in[1];
    const int*   dst = (const int*)d_in[2];
    const float* W1  = (const float*)d_in[3];
    const float* b1  = (const float*)d_in[4];
    const float* W2  = (const float*)d_in[5];
    const float* b2  = (const float*)d_in[6];
    float* out = (float*)d_out;

    // ws: counts [50000 int] | w1sw [65536 bf16] | w2sw [32768 bf16] |
    //     ht [50001 x 128 bf16]  (row 50000 = zero sentinel)
    // total ~13.2 MB (bucket lives in d_out).
    int* counts = (int*)d_ws;
    unsigned short* w1sw = (unsigned short*)(counts + N_NODES);
    unsigned short* w2sw = w1sw + 65536;
    unsigned short* ht   = w2sw + 32768;   // 16B aligned

    hipMemsetAsync(counts, 0, N_NODES * sizeof(int), stream);

    sage_prep<<<NB_PREP, 256, 0, stream>>>(
        src, dst, counts, (char*)d_out, h, ht, W1, W2, w1sw, w2sw);

    sage_fused<<<NB_MLP, 256, 0, stream>>>(counts, ht, w1sw, w2sw, b1, b2, out);
}

// Round 6
// 166.505 us; speedup vs baseline: 1.1092x; 1.0184x over previous
//
#include <hip/hip_runtime.h>

#define N_NODES 50000
#define E_EDGES 600000
#define IN_DIM  128
#define HID     256
#define OUT_DIM 128
#define CAP     64     // bucket capacity (deg ~ Poisson(12), max ~35); 64*4B = 256B d_out slot
#define ZROW    N_NODES   // sentinel ht row of zeros (row 50000)

#define RANGE_N 6250   // N_NODES / 8 ranges (one per XCD, heuristically)
#define CHUNK_E 2048   // edges per fill block (8/thread)
#define NB_FILL 2344   // 293 chunks x 8 ranges; 293*2048 = 600064 >= E
#define NB_HCVT 3125   // N*16/256, 8 floats/thread
#define NB_WCVT 384    // (65536+32768)/256
#define NB_PREP (NB_FILL + NB_HCVT + NB_WCVT + 1)   // 5854 (last block zeroes ZROW)
#define NB_MLP  1563   // (N_NODES+31)/32  -- 32-row blocks: 6.1 blocks/CU
#define BROWS   32

typedef __bf16 bf16x8 __attribute__((ext_vector_type(8)));
typedef float  f32x16 __attribute__((ext_vector_type(16)));
typedef unsigned short ushort8 __attribute__((ext_vector_type(8)));

__device__ __forceinline__ unsigned short f2bf(float f) {
    union { float f; unsigned int i; } v; v.f = f;
    unsigned int b = v.i;
    b += 0x7fffu + ((b >> 16) & 1u);   // RNE
    return (unsigned short)(b >> 16);
}
// accumulate 2 packed bf16 (one uint) into two f32 accumulators: 4 VALU insts
__device__ __forceinline__ void acc2(unsigned u, float& a0, float& a1) {
    union { unsigned i; float f; } lo, hi;
    lo.i = u << 16; hi.i = u & 0xffff0000u;
    a0 += lo.f; a1 += hi.f;
}

// ---------------------------------------------------------------------------
// Prep (unchanged from r5): [XCD-local bucket fill] + [h fp32->bf16] +
// [W -> swz bf16] + [zero sentinel row].
// Fill: block b -> range r = b&7 (nodes [r*6250,(r+1)*6250)), chunk b>>3 of
// 2048 edges; under round-robin block->XCD dispatch each bucket line + count
// is owned by one XCD's L2. Correct under ANY placement.
// Bucket lives in d_out: node n slots at bytes [n*512+256, n*512+512).
//   w1sw flat = (((c*4 + ks)*2 + g)*256 + n)*8 + j,  k = c*64 + ks*16 + g*8 + j
//   w2sw flat = (((c*8 + ks)*2 + g)*128 + n)*8 + j,  k = c*128 + ks*16 + g*8 + j
// ---------------------------------------------------------------------------
__global__ void __launch_bounds__(256)
sage_prep(const int* __restrict__ src, const int* __restrict__ dst,
          int* __restrict__ counts, char* __restrict__ outb,
          const float* __restrict__ h, unsigned short* __restrict__ ht,
          const float* __restrict__ W1, const float* __restrict__ W2,
          unsigned short* __restrict__ w1sw, unsigned short* __restrict__ w2sw) {
    int b = blockIdx.x;
    if (b < NB_FILL) {
        int r = b & 7;
        int chunk = b >> 3;
        int e0 = chunk * CHUNK_E + threadIdx.x * 8;
        if (e0 < E_EDGES) {            // E % 8 == 0 -> whole 8-group in/out together
            int lo = r * RANGE_N, hi = lo + RANGE_N;
            const int4 d0 = *(const int4*)(dst + e0);
            const int4 d1 = *(const int4*)(dst + e0 + 4);
            int dd[8] = {d0.x, d0.y, d0.z, d0.w, d1.x, d1.y, d1.z, d1.w};
            #pragma unroll
            for (int k = 0; k < 8; ++k) {
                int d = dd[k];
                if (d >= lo && d < hi) {
                    int s = src[e0 + k];
                    int sl = atomicAdd(counts + d, 1);
                    if (sl < CAP) *((int*)(outb + (size_t)d * 512 + 256) + sl) = s;
                }
            }
        }
    } else if (b < NB_FILL + NB_HCVT) {
        int idx = (b - NB_FILL) * 256 + threadIdx.x;   // < 800000 exactly
        int n = idx >> 4, g = idx & 15;                 // 16 threads/node, 8 f/thread
        const float4 v0 = *(const float4*)(h + (size_t)n * IN_DIM + g * 8);
        const float4 v1 = *(const float4*)(h + (size_t)n * IN_DIM + g * 8 + 4);
        ushort8 o;
        o[0] = f2bf(v0.x); o[1] = f2bf(v0.y); o[2] = f2bf(v0.z); o[3] = f2bf(v0.w);
        o[4] = f2bf(v1.x); o[5] = f2bf(v1.y); o[6] = f2bf(v1.z); o[7] = f2bf(v1.w);
        *(ushort8*)(ht + (size_t)n * 128 + g * 8) = o;
    } else if (b < NB_FILL + NB_HCVT + NB_WCVT) {
        int i1 = (b - NB_FILL - NB_HCVT) * 256 + threadIdx.x;
        if (i1 < 65536) {
            int j = i1 & 7, n = (i1 >> 3) & 255, g = (i1 >> 11) & 1, ks = (i1 >> 12) & 3, c = i1 >> 14;
            int k = c * 64 + ks * 16 + g * 8 + j;
            w1sw[i1] = f2bf(W1[(size_t)k * HID + n]);
        } else {
            int i2 = i1 - 65536;
            int j = i2 & 7, n = (i2 >> 3) & 127, g = (i2 >> 10) & 1, ks = (i2 >> 11) & 7, c = (i2 >> 14) & 1;
            int k = c * 128 + ks * 16 + g * 8 + j;
            w2sw[i2] = f2bf(W2[(size_t)k * OUT_DIM + n]);
        }
    } else {
        // zero the sentinel row (ht row ZROW = 50000): dead gather slots load it
        if (threadIdx.x < 64)
            *(unsigned*)(ht + (size_t)ZROW * 128 + threadIdx.x * 2) = 0u;
    }
}

// ---------------------------------------------------------------------------
// Fused gather + 2-layer MLP — 32-ROW BLOCKS (r6 change). Grid 1563 blocks,
// LDS 16.9 KB, launch_bounds(256,6) -> 6 blocks/CU resident (24 waves/CU,
// ~3x r5's 8.5) for the latency-bound gather. Weights stay L2-hot; per-block
// weight re-read doubles but is L2 traffic only.
// Phase G (unchanged structure): branch-free wave-per-node coalesced rows,
//   4 nodes interleaved x 2 groups = 8 nodes/wave; dead slots load the zero
//   sentinel row via scalar cselect (straight-line, 16 loads in flight).
//   Self rows copied to hid_s[m][128:256]; means to hid_s[m][0:128].
// Layer 1: A (32x256) from LDS, B from L2-hot w1sw. Wave nw owns cols
//   nw*64..+63 (nt in {0,1}): 32 MFMA/wave. Layer 2: wave nw owns out cols
//   nw*32..+31: 16 MFMA/wave.
// Layouts: A[m=lane&31][k=(lane>>5)*8+j], B[k][n=lane&31],
//   C/D col=lane&31, row=(reg&3)+8*(reg>>2)+4*(lane>>5).
// Bucket rows (d_out, node n at n*512+256) are read before the same block's
// fp32 out write clobbers row n's 512B: reads precede first barrier, stores
// after 3 barriers; only the owning block touches row n's bytes.
// ---------------------------------------------------------------------------
__global__ void __launch_bounds__(256, 6)
sage_fused(const int* __restrict__ counts,
           const unsigned short* __restrict__ ht,     // ws: bf16 [N+1][128]
           const unsigned short* __restrict__ w1sw,
           const unsigned short* __restrict__ w2sw,
           const float* __restrict__ b1,
           const float* __restrict__ b2,
           float* out) {                              // d_out (also holds bucket)
    __shared__ unsigned short hid_s[BROWS][264];  // 16.9 KB: [0:128)=means, [128:256)=self

    const int t = threadIdx.x;
    const int nw = t >> 6;
    const int lane = t & 63;
    const int lr = lane & 31;
    const int lg = lane >> 5;
    const int base = blockIdx.x * BROWS;

    // ---- Phase G: branch-free coalesced gather, 8 nodes/wave (2 groups) ----
    {
        #pragma unroll 1
        for (int g = 0; g < 2; ++g) {
            const int m0 = nw * 8 + g * 4;
            float a0[4], a1[4];
            int deg[4], ent[4];
            const int* bk[4];
            int4 q[4];
            int em = 0;
            #pragma unroll
            for (int j = 0; j < 4; ++j) {
                a0[j] = 0.f; a1[j] = 0.f;
                int node = min(base + m0 + j, N_NODES - 1);  // tail rows: dup gather, never stored
                deg[j] = __builtin_amdgcn_readfirstlane(counts[node]);
                ent[j] = min(deg[j], CAP);
                em = max(em, ent[j]);
                bk[j] = (const int*)((const char*)out + (size_t)node * 512 + 256);
                q[j] = *(const int4*)(bk[j]);       // slots 0..3 (allocated; sel-guarded use)
                // own row -> hid_s[m][128:256] (coalesced; hidden among gather loads)
                unsigned self = *(const unsigned*)(ht + (size_t)node * 128 + lane * 2);
                *(unsigned*)(&hid_s[m0 + j][128 + lane * 2]) = self;
            }
            #pragma unroll 1
            for (int p = 0; p < em; p += 4) {
                int4 nx[4];
                #pragma unroll
                for (int j = 0; j < 4; ++j)
                    nx[j] = *(const int4*)(bk[j] + min(p + 4, CAP - 4));  // prefetch (sel-guarded use)
                unsigned uu[16];
                // pass 1: 16 unconditional loads; dead slots -> zero sentinel row
                #pragma unroll
                for (int k = 0; k < 4; ++k) {
                    #pragma unroll
                    for (int j = 0; j < 4; ++j) {
                        int idx = (k == 0) ? q[j].x : (k == 1) ? q[j].y
                                : (k == 2) ? q[j].z : q[j].w;
                        idx = __builtin_amdgcn_readfirstlane(idx);
                        idx = (p + k < ent[j]) ? idx : ZROW;   // scalar cselect, no branch
                        uu[k * 4 + j] = *(const unsigned*)(ht + (size_t)idx * 128 + lane * 2);
                    }
                }
                // pass 2: unconditional accumulate (sentinel adds 0.0)
                #pragma unroll
                for (int k = 0; k < 4; ++k) {
                    #pragma unroll
                    for (int j = 0; j < 4; ++j)
                        acc2(uu[k * 4 + j], a0[j], a1[j]);
                }
                #pragma unroll
                for (int j = 0; j < 4; ++j) q[j] = nx[j];
            }
            #pragma unroll
            for (int j = 0; j < 4; ++j) {
                float inv = 1.0f / (float)max(deg[j], 1);
                unsigned o = (unsigned)f2bf(a0[j] * inv) | ((unsigned)f2bf(a1[j] * inv) << 16);
                *(unsigned*)(&hid_s[m0 + j][lane * 2]) = o;
            }
        }
    }

    __syncthreads();    // gather writes (means + self rows) visible to all waves

    // ---- Layer 1: hid = A (32x256) @ W1 (256x256); A from LDS, B from L2 ---
    f32x16 c1[2];   // [nt]
    #pragma unroll
    for (int e2 = 0; e2 < 16; ++e2) { c1[0][e2] = 0.f; c1[1][e2] = 0.f; }

    #pragma unroll
    for (int c = 0; c < 4; ++c) {
        bf16x8 a0[4];
        #pragma unroll
        for (int ks = 0; ks < 4; ++ks) {
            // k 0..127 = self features (LDS col 128+), k 128..255 = means (LDS col 0+)
            int koff = (c < 2) ? (128 + c * 64 + ks * 16 + lg * 8)
                               : ((c - 2) * 64 + ks * 16 + lg * 8);
            a0[ks] = *(const bf16x8*)(&hid_s[lr][koff]);
        }
        #pragma unroll
        for (int ks = 0; ks < 4; ++ks) {
            #pragma unroll
            for (int nt = 0; nt < 2; ++nt) {
                int n = nw * 64 + nt * 32 + lr;
                bf16x8 b = *(const bf16x8*)(w1sw + c * 16384 + (((ks * 2 + lg) * 256) + n) * 8);
                c1[nt] = __builtin_amdgcn_mfma_f32_32x32x16_bf16(a0[ks], b, c1[nt], 0, 0, 0);
            }
        }
    }

    __syncthreads();    // all A reads done before epilogue-1 overwrites

    // ---- epilogue 1: + b1 -> bf16 -> hid_s (row-major [m][k]) --------------
    #pragma unroll
    for (int nt = 0; nt < 2; ++nt) {
        int col = nw * 64 + nt * 32 + lr;
        float bias = b1[col];
        #pragma unroll
        for (int reg = 0; reg < 16; ++reg) {
            int m = (reg & 3) + 8 * (reg >> 2) + 4 * lg;
            hid_s[m][col] = f2bf(c1[nt][reg] + bias);
        }
    }
    __syncthreads();    // hidden tile visible

    // ---- Layer 2: out = hid (32x256) @ W2 (256x128), B direct from global --
    f32x16 c2;
    #pragma unroll
    for (int e2 = 0; e2 < 16; ++e2) c2[e2] = 0.f;

    #pragma unroll
    for (int c = 0; c < 2; ++c) {
        #pragma unroll
        for (int ks = 0; ks < 8; ++ks) {
            bf16x8 b = *(const bf16x8*)(w2sw + c * 16384 + ((ks * 2 + lg) * 128 + nw * 32 + lr) * 8);
            int koff = c * 128 + ks * 16 + lg * 8;
            bf16x8 ah0 = *(const bf16x8*)(&hid_s[lr][koff]);
            c2 = __builtin_amdgcn_mfma_f32_32x32x16_bf16(ah0, b, c2, 0, 0, 0);
        }
    }

    // ---- epilogue 2: + b2, relu, store fp32 (clobbers own bucket rows only)
    {
        int col = nw * 32 + lr;
        float bias = b2[col];
        #pragma unroll
        for (int reg = 0; reg < 16; ++reg) {
            int m = (reg & 3) + 8 * (reg >> 2) + 4 * lg;
            int n = base + m;
            if (n < N_NODES)
                out[(size_t)n * OUT_DIM + col] = fmaxf(c2[reg] + bias, 0.0f);
        }
    }
}

extern "C" void kernel_launch(void* const* d_in, const int* in_sizes, int n_in,
                              void* d_out, int out_size, void* d_ws, size_t ws_size,
                              hipStream_t stream) {
    const float* h   = (const float*)d_in[0];
    const int*   src = (const int*)d_in[1];
    const int*   dst = (const int*)d_in[2];
    const float* W1  = (const float*)d_in[3];
    const float* b1  = (const float*)d_in[4];
    const float* W2  = (const float*)d_in[5];
    const float* b2  = (const float*)d_in[6];
    float* out = (float*)d_out;

    // ws: counts [50000 int] | w1sw [65536 bf16] | w2sw [32768 bf16] |
    //     ht [50001 x 128 bf16]  (row 50000 = zero sentinel)
    // total ~13.2 MB (bucket lives in d_out).
    int* counts = (int*)d_ws;
    unsigned short* w1sw = (unsigned short*)(counts + N_NODES);
    unsigned short* w2sw = w1sw + 65536;
    unsigned short* ht   = w2sw + 32768;   // 16B aligned

    hipMemsetAsync(counts, 0, N_NODES * sizeof(int), stream);

    sage_prep<<<NB_PREP, 256, 0, stream>>>(
        src, dst, counts, (char*)d_out, h, ht, W1, W2, w1sw, w2sw);

    sage_fused<<<NB_MLP, 256, 0, stream>>>(counts, ht, w1sw, w2sw, b1, b2, out);
}